// Round 16
// baseline (474.383 us; speedup 1.0000x reference)
//
#include <hip/hip_runtime.h>

#define Bb 8
#define Nn 2048
#define Dd 512

#define KV 32            // keys per tile/image
#define NT 64            // images per batch
#define PP2 40           // sP row stride (elements)

// fallback (no ws): R10 structure
#define KVF 64
#define NTF (Nn / KVF)
#define PPF 72

typedef __attribute__((ext_vector_type(8))) short bf8;
typedef __attribute__((ext_vector_type(4))) float f4;
struct __align__(16) U8 { unsigned short s[8]; };

__device__ __forceinline__ unsigned short f2bf(float f) {
  union { float f; unsigned u; } v; v.f = f;
  unsigned r = v.u + 0x7fffu + ((v.u >> 16) & 1u);
  return (unsigned short)(r >> 16);
}

// ---------------------------------------------------------------------------
// Build per-(b,tile) images in ws, once.  Image = [K 16384 | Vt 16384] u16.
//   K : key*512 + ((c ^ (key&7))<<3), c = d>>3        (LDS-swizzled row-major)
//   Vt: 16384 + d*32 + ((g ^ ((d>>1)&3))<<3), g = key>>3  (transpose)
// ---------------------------------------------------------------------------
__global__ __launch_bounds__(256)
void build_images(const float* __restrict__ X, unsigned short* __restrict__ W) {
  __shared__ float sT[KV * Dd];  // 64 KB
  const int t = blockIdx.x, b = blockIdx.y, tid = threadIdx.x;
  const float* src = X + ((size_t)b * Nn + t * KV) * Dd;
#pragma unroll
  for (int i = 0; i < 16; ++i) {
    int idx = i * 256 + tid;
    *(float4*)(sT + idx * 4) = *(const float4*)(src + idx * 4);
  }
  __syncthreads();
  unsigned short* img = W + ((size_t)(b * NT + t) << 15);
#pragma unroll
  for (int i = 0; i < 8; ++i) {
    int idx = i * 256 + tid;
    int key = idx >> 6, c = idx & 63;
    const float* p = sT + key * Dd + c * 8;
    U8 v;
#pragma unroll
    for (int j = 0; j < 8; ++j) v.s[j] = f2bf(p[j]);
    *(U8*)(img + key * 512 + ((c ^ (key & 7)) << 3)) = v;
  }
#pragma unroll
  for (int i = 0; i < 8; ++i) {
    int idx = i * 256 + tid;
    int d = idx >> 2, g = idx & 3;
    U8 v;
#pragma unroll
    for (int e = 0; e < 8; ++e) v.s[e] = f2bf(sT[(g * 8 + e) * Dd + d]);
    *(U8*)(img + 16384 + d * 32 + ((g ^ ((d >> 1) & 3)) << 3)) = v;
  }
}

// ---------------------------------------------------------------------------
// Attention over a key range. 256 thr = 4 waves x 16 q-rows.
// LDS = K-image (32 KB) + sP (5 KB) = 37.9 KB -> 2 blocks/CU co-resident.
// V fragments read DIRECTLY from the Vt image via L2 (coalesced 16B/lane).
// K staged in two 16 KB register half-stages; 2 barriers/tile.
// __launch_bounds__(256, 1): the 2nd arg sets the VGPR cap directly —
// (256,2) capped at 128 VGPR and spilled ~460 MB (R15); (256,1) gives ~200
// VGPR no-spill (R14), and 200 <= 256 still admits 2 waves/SIMD at runtime.
// ---------------------------------------------------------------------------
template <int HALVES>
__global__ __launch_bounds__(256, 1)
void attn_part(const unsigned short* __restrict__ W, const int* __restrict__ mask,
               float* __restrict__ O0, float* __restrict__ O1,
               float* __restrict__ ML) {
  __shared__ unsigned short sImg[16384];      // K image only, 32 KB
  __shared__ unsigned short sP[4][16 * PP2];  // 5 KB

  const int tid  = threadIdx.x;
  const int wave = tid >> 6, lane = tid & 63;
  const int lg = lane >> 4, ll = lane & 15;
  const int bid = blockIdx.x;
  const int b    = bid & 7;                   // XCD-batch affinity
  const int qb   = (bid >> 3) & 31;
  const int half = (HALVES == 2) ? (bid >> 8) : 0;
  const int NTT  = (HALVES == 2) ? 32 : 64;
  const int t0   = half * NTT;
  const int q0 = qb * 64 + wave * 16;
  const int bN = b * NT;
  const float scale = 0.044194173824159216f;  // 1/sqrt(512)

  // Q fragments from the K-images (same layout math as K reads)
  bf8 qf[16];
  {
    int qrow = q0 + ll;
    const unsigned short* qimg = W + ((size_t)(bN + (qrow >> 5)) << 15);
    int key = qrow & 31;
#pragma unroll
    for (int ch = 0; ch < 16; ++ch) {
      int c = ch * 4 + lg;
      qf[ch] = *(const bf8*)(qimg + key * 512 + ((c ^ (key & 7)) << 3));
    }
  }

  float bias[4];
#pragma unroll
  for (int r = 0; r < 4; ++r)
    bias[r] = (1.0f - (float)mask[b * Nn + q0 + lg * 4 + r]) * 1e9f;

  float m[4], lsum[4];
  f4 o[32];
#pragma unroll
  for (int r = 0; r < 4; ++r) { m[r] = -1e30f; lsum[r] = 0.0f; }
#pragma unroll
  for (int ct = 0; ct < 32; ++ct) o[ct] = (f4){0.f, 0.f, 0.f, 0.f};

  // prologue: stage first K tile (32 KB = 8 x 16B per thread)
  {
    const unsigned short* img0 = W + ((size_t)(bN + t0) << 15);
#pragma unroll
    for (int i = 0; i < 8; ++i) {
      U8 v = *(const U8*)(img0 + (i * 256 + tid) * 8);
      *(U8*)(sImg + (i * 256 + tid) * 8) = v;
    }
  }
  __syncthreads();

  for (int tt = 0; tt < NTT; ++tt) {
    const bool pf = (tt + 1 < NTT);
    const unsigned short* gKn = W + ((size_t)(bN + t0 + tt + 1) << 15);

    // prefetch first 16 KB of next K tile (hides under QK^T)
    U8 stH[4];
    if (pf) {
#pragma unroll
      for (int j = 0; j < 4; ++j) stH[j] = *(const U8*)(gKn + (j * 256 + tid) * 8);
    }

    // ---- QK^T: S[16 x 32] ----
    f4 s2[2];
    s2[0] = (f4){0.f, 0.f, 0.f, 0.f};
    s2[1] = (f4){0.f, 0.f, 0.f, 0.f};
#pragma unroll
    for (int ch = 0; ch < 16; ++ch) {
#pragma unroll
      for (int cc = 0; cc < 2; ++cc) {
        int key = cc * 16 + ll;
        bf8 kf = *(const bf8*)(sImg + key * 512 + (((ch * 4 + lg) ^ (key & 7)) << 3));
        s2[cc] = __builtin_amdgcn_mfma_f32_16x16x32_bf16(qf[ch], kf, s2[cc], 0, 0, 0);
      }
    }
    __syncthreads();  // bar1: all waves done reading K

    // write first half, issue second half (in flight across softmax)
    U8 stH2[4];
    if (pf) {
#pragma unroll
      for (int j = 0; j < 4; ++j) *(U8*)(sImg + (j * 256 + tid) * 8) = stH[j];
#pragma unroll
      for (int j = 0; j < 4; ++j) stH2[j] = *(const U8*)(gKn + ((j + 4) * 256 + tid) * 8);
    }

    // ---- online softmax ----
    float e2[2][4];
#pragma unroll
    for (int cc = 0; cc < 2; ++cc)
#pragma unroll
      for (int r = 0; r < 4; ++r)
        e2[cc][r] = s2[cc][r] * scale - bias[r];  // f32: masked rows -> exactly -1e9

    float tm[4];
#pragma unroll
    for (int r = 0; r < 4; ++r) tm[r] = fmaxf(e2[0][r], e2[1][r]);
#pragma unroll
    for (int off = 1; off < 16; off <<= 1)
#pragma unroll
      for (int r = 0; r < 4; ++r) tm[r] = fmaxf(tm[r], __shfl_xor(tm[r], off));

    float mn[4];
    bool change = false;
#pragma unroll
    for (int r = 0; r < 4; ++r) { mn[r] = fmaxf(m[r], tm[r]); change = change || (mn[r] > m[r]); }
    if (__any(change)) {
#pragma unroll
      for (int r = 0; r < 4; ++r) {
        float al = __expf(m[r] - mn[r]);
        lsum[r] *= al;
        m[r] = mn[r];
#pragma unroll
        for (int ct = 0; ct < 32; ++ct) o[ct][r] *= al;
      }
    }

    float ts[4] = {0.f, 0.f, 0.f, 0.f};
    unsigned short pb[2][4];
#pragma unroll
    for (int cc = 0; cc < 2; ++cc)
#pragma unroll
      for (int r = 0; r < 4; ++r) {
        float p = __expf(e2[cc][r] - m[r]);
        ts[r] += p;
        pb[cc][r] = f2bf(p);
      }
#pragma unroll
    for (int off = 1; off < 16; off <<= 1)
#pragma unroll
      for (int r = 0; r < 4; ++r) ts[r] += __shfl_xor(ts[r], off);
#pragma unroll
    for (int r = 0; r < 4; ++r) lsum[r] += ts[r];

    // write second half of next K tile (loads have had softmax to land)
    if (pf) {
#pragma unroll
      for (int j = 0; j < 4; ++j) *(U8*)(sImg + ((j + 4) * 256 + tid) * 8) = stH2[j];
    }

    // ---- P round-trip (same wave, no barrier) ----
    unsigned short* Pw = sP[wave];
#pragma unroll
    for (int cc = 0; cc < 2; ++cc)
#pragma unroll
      for (int r = 0; r < 4; ++r)
        Pw[(lg * 4 + r) * PP2 + cc * 16 + ll] = pb[cc][r];
    bf8 af = *(const bf8*)(Pw + ll * PP2 + lg * 8);

    // ---- PV: V fragments straight from L2 (coalesced 16B/lane) ----
    const unsigned short* gV = W + ((size_t)(bN + t0 + tt) << 15) + 16384;
    bf8 va[4];
#pragma unroll
    for (int g = 0; g < 8; ++g) {
#pragma unroll
      for (int j = 0; j < 4; ++j) {
        int ct = g * 4 + j;
        int d = ct * 16 + ll;
        va[j] = *(const bf8*)(gV + d * 32 + ((lg ^ ((d >> 1) & 3)) << 3));
      }
#pragma unroll
      for (int j = 0; j < 4; ++j) {
        int ct = g * 4 + j;
        o[ct] = __builtin_amdgcn_mfma_f32_16x16x32_bf16(af, va[j], o[ct], 0, 0, 0);
      }
    }
    __syncthreads();  // bar2: K writes visible before next QK^T
  }

  if (HALVES == 1) {
    float inv[4];
#pragma unroll
    for (int r = 0; r < 4; ++r) inv[r] = 1.0f / lsum[r];
#pragma unroll
    for (int ct = 0; ct < 32; ++ct)
#pragma unroll
      for (int r = 0; r < 4; ++r) {
        size_t row = (size_t)b * Nn + q0 + lg * 4 + r;
        O0[row * Dd + ct * 16 + ll] = o[ct][r] * inv[r];
      }
  } else {
    float* Od = half ? O1 : O0;
#pragma unroll
    for (int ct = 0; ct < 32; ++ct)
#pragma unroll
      for (int r = 0; r < 4; ++r) {
        size_t row = (size_t)b * Nn + q0 + lg * 4 + r;
        Od[row * Dd + ct * 16 + ll] = o[ct][r];
      }
    if (ll == 0) {
#pragma unroll
      for (int r = 0; r < 4; ++r) {
        int gr = b * Nn + q0 + lg * 4 + r;
        ML[(half * (Bb * Nn) + gr) * 2 + 0] = m[r];
        ML[(half * (Bb * Nn) + gr) * 2 + 1] = lsum[r];
      }
    }
  }
}

// ---------------------------------------------------------------------------
// Flash merge of the two key-halves: out = (a0*O0 + a1*O1) / (a0*l0 + a1*l1).
// ---------------------------------------------------------------------------
__global__ __launch_bounds__(256)
void merge_halves(float* __restrict__ O0, const float* __restrict__ O1,
                  const float* __restrict__ ML) {
#pragma unroll
  for (int k = 0; k < 4; ++k) {
    int i4 = blockIdx.x * 1024 + k * 256 + threadIdx.x;  // float4 index
    int gr = i4 >> 7;                                    // global row
    float m0 = ML[gr * 2 + 0], l0 = ML[gr * 2 + 1];
    float m1 = ML[(Bb * Nn + gr) * 2 + 0], l1 = ML[(Bb * Nn + gr) * 2 + 1];
    float M  = fmaxf(m0, m1);
    float a0 = __expf(m0 - M), a1 = __expf(m1 - M);
    float inv = 1.0f / (a0 * l0 + a1 * l1);
    float4 v0 = *(float4*)(O0 + (size_t)i4 * 4);
    float4 v1 = *(const float4*)(O1 + (size_t)i4 * 4);
    float4 w;
    w.x = (a0 * v0.x + a1 * v1.x) * inv;
    w.y = (a0 * v0.y + a1 * v1.y) * inv;
    w.z = (a0 * v0.z + a1 * v1.z) * inv;
    w.w = (a0 * v0.w + a1 * v1.w) * inv;
    *(float4*)(O0 + (size_t)i4 * 4) = w;
  }
}

// ---------------------------------------------------------------------------
// Fallback (no usable ws): R10 structure, KV=64, in-kernel convert.
// ---------------------------------------------------------------------------
__global__ __launch_bounds__(256, 1)
void attn_fb(const float* __restrict__ Xf, const int* __restrict__ mask,
             float* __restrict__ out) {
  __shared__ unsigned short sK[KVF * Dd];
  __shared__ unsigned short sVt[Dd * KVF];
  __shared__ unsigned short sPf[4][16 * PPF];

  const int tid  = threadIdx.x;
  const int wave = tid >> 6, lane = tid & 63;
  const int lg = lane >> 4, ll = lane & 15;
  const int b  = blockIdx.y;
  const int q0 = blockIdx.x * 64 + wave * 16;

  bf8 qf[16];
  {
    const size_t qoff = ((size_t)b * Nn + q0 + ll) * Dd;
#pragma unroll
    for (int ch = 0; ch < 16; ++ch) {
      int doff = ch * 32 + lg * 8;
      float4 a = *(const float4*)(Xf + qoff + doff);
      float4 c = *(const float4*)(Xf + qoff + doff + 4);
      bf8 tt;
      tt[0] = (short)f2bf(a.x); tt[1] = (short)f2bf(a.y);
      tt[2] = (short)f2bf(a.z); tt[3] = (short)f2bf(a.w);
      tt[4] = (short)f2bf(c.x); tt[5] = (short)f2bf(c.y);
      tt[6] = (short)f2bf(c.z); tt[7] = (short)f2bf(c.w);
      qf[ch] = tt;
    }
  }
  float bias[4];
#pragma unroll
  for (int r = 0; r < 4; ++r)
    bias[r] = (1.0f - (float)mask[b * Nn + q0 + lg * 4 + r]) * 1e9f;
  float m[4], lsum[4];
  f4 o[32];
#pragma unroll
  for (int r = 0; r < 4; ++r) { m[r] = -1e30f; lsum[r] = 0.0f; }
#pragma unroll
  for (int ct = 0; ct < 32; ++ct) o[ct] = (f4){0.f, 0.f, 0.f, 0.f};
  const float scale = 0.044194173824159216f;

  for (int t = 0; t < NTF; ++t) {
    __syncthreads();
    const size_t base = ((size_t)b * Nn + t * KVF) * Dd;
#pragma unroll
    for (int it = 0; it < 16; ++it) {
      int idx = it * 256 + tid;
      int key = idx >> 6, c = idx & 63;
      const float* sp = Xf + base + key * Dd + c * 8;
      float4 a = *(const float4*)(sp);
      float4 d2 = *(const float4*)(sp + 4);
      U8 v;
      v.s[0] = f2bf(a.x); v.s[1] = f2bf(a.y); v.s[2] = f2bf(a.z); v.s[3] = f2bf(a.w);
      v.s[4] = f2bf(d2.x); v.s[5] = f2bf(d2.y); v.s[6] = f2bf(d2.z); v.s[7] = f2bf(d2.w);
      *(U8*)(sK + key * 512 + ((c ^ (key & 7)) << 3)) = v;
      int ko = key >> 3, k7 = key & 7;
#pragma unroll
      for (int j = 0; j < 8; ++j) {
        int dd = c * 8 + j;
        sVt[dd * 64 + ((ko ^ j ^ (c & 7)) << 3) + k7] = v.s[j];
      }
    }
    __syncthreads();

    f4 s[4];
#pragma unroll
    for (int cc = 0; cc < 4; ++cc) s[cc] = (f4){0.f, 0.f, 0.f, 0.f};
#pragma unroll
    for (int ch = 0; ch < 16; ++ch)
#pragma unroll
      for (int cc = 0; cc < 4; ++cc) {
        int key = cc * 16 + ll;
        bf8 kf = *(const bf8*)(sK + key * 512 + (((ch * 4 + lg) ^ (key & 7)) << 3));
        s[cc] = __builtin_amdgcn_mfma_f32_16x16x32_bf16(qf[ch], kf, s[cc], 0, 0, 0);
      }

    float e[4][4];
#pragma unroll
    for (int cc = 0; cc < 4; ++cc)
#pragma unroll
      for (int r = 0; r < 4; ++r) e[cc][r] = s[cc][r] * scale - bias[r];
    float tm[4];
#pragma unroll
    for (int r = 0; r < 4; ++r)
      tm[r] = fmaxf(fmaxf(e[0][r], e[1][r]), fmaxf(e[2][r], e[3][r]));
#pragma unroll
    for (int off = 1; off < 16; off <<= 1)
#pragma unroll
      for (int r = 0; r < 4; ++r) tm[r] = fmaxf(tm[r], __shfl_xor(tm[r], off));
    float mn[4]; bool change = false;
#pragma unroll
    for (int r = 0; r < 4; ++r) { mn[r] = fmaxf(m[r], tm[r]); change = change || (mn[r] > m[r]); }
    if (__any(change)) {
#pragma unroll
      for (int r = 0; r < 4; ++r) {
        float al = __expf(m[r] - mn[r]);
        lsum[r] *= al; m[r] = mn[r];
#pragma unroll
        for (int ct = 0; ct < 32; ++ct) o[ct][r] *= al;
      }
    }
    float ts[4] = {0.f, 0.f, 0.f, 0.f};
    unsigned short pb[4][4];
#pragma unroll
    for (int cc = 0; cc < 4; ++cc)
#pragma unroll
      for (int r = 0; r < 4; ++r) {
        float p = __expf(e[cc][r] - m[r]);
        ts[r] += p; pb[cc][r] = f2bf(p);
      }
#pragma unroll
    for (int off = 1; off < 16; off <<= 1)
#pragma unroll
      for (int r = 0; r < 4; ++r) ts[r] += __shfl_xor(ts[r], off);
#pragma unroll
    for (int r = 0; r < 4; ++r) lsum[r] += ts[r];

    unsigned short* Pw = sPf[wave];
#pragma unroll
    for (int cc = 0; cc < 4; ++cc)
#pragma unroll
      for (int r = 0; r < 4; ++r)
        Pw[(lg * 4 + r) * PPF + cc * 16 + ll] = pb[cc][r];
#pragma unroll
    for (int kc = 0; kc < 2; ++kc) {
      bf8 af = *(const bf8*)(Pw + ll * PPF + kc * 32 + lg * 8);
#pragma unroll
      for (int ct = 0; ct < 32; ++ct) {
        int d = ct * 16 + ll;
        bf8 vf = *(const bf8*)(sVt + d * 64 + (((kc * 4 + lg) ^ (d & 7) ^ ((d >> 3) & 7)) << 3));
        o[ct] = __builtin_amdgcn_mfma_f32_16x16x32_bf16(af, vf, o[ct], 0, 0, 0);
      }
    }
  }
  float inv[4];
#pragma unroll
  for (int r = 0; r < 4; ++r) inv[r] = 1.0f / lsum[r];
#pragma unroll
  for (int ct = 0; ct < 32; ++ct)
#pragma unroll
    for (int r = 0; r < 4; ++r) {
      size_t row = (size_t)b * Nn + q0 + lg * 4 + r;
      out[row * Dd + ct * 16 + ll] = o[ct][r] * inv[r];
    }
}

extern "C" void kernel_launch(void* const* d_in, const int* in_sizes, int n_in,
                              void* d_out, int out_size, void* d_ws, size_t ws_size,
                              hipStream_t stream) {
  (void)in_sizes; (void)n_in; (void)out_size;
  const float* X  = (const float*)d_in[0];
  const int* mask = (const int*)d_in[1];
  float* out = (float*)d_out;

  const size_t szImg = (size_t)Bb * NT * 65536;        // 32 MiB images
  const size_t szO   = (size_t)Bb * Nn * Dd * 4;       // 32 MiB partial O
  const size_t szML  = (size_t)2 * Bb * Nn * 2 * 4;    // 256 KiB m/l
  if (ws_size >= szImg + szO + szML) {
    unsigned short* W = (unsigned short*)d_ws;
    float* O1 = (float*)((char*)d_ws + szImg);
    float* ML = (float*)((char*)d_ws + szImg + szO);
    build_images<<<dim3(NT, Bb), 256, 0, stream>>>(X, W);
    attn_part<2><<<512, 256, 0, stream>>>(W, mask, out, O1, ML);
    merge_halves<<<2048, 256, 0, stream>>>(out, O1, ML);
  } else if (ws_size >= szImg) {
    unsigned short* W = (unsigned short*)d_ws;
    build_images<<<dim3(NT, Bb), 256, 0, stream>>>(X, W);
    attn_part<1><<<256, 256, 0, stream>>>(W, mask, out, nullptr, nullptr);
  } else {
    attn_fb<<<dim3(Nn / 64, Bb), 256, 0, stream>>>(X, mask, out);
  }
}

// Round 17
// 309.089 us; speedup vs baseline: 1.5348x; 1.5348x over previous
//
#include <hip/hip_runtime.h>

#define Bb 8
#define Nn 2048
#define Dd 512

#define KV 32            // keys per tile/image
#define NT 64            // images per batch
#define PPS 42           // sP row stride (u16 elements; 84B -> conflict-light)

// fallback (no ws): R10 structure
#define KVF 64
#define NTF (Nn / KVF)
#define PPF 72

typedef __attribute__((ext_vector_type(8))) short bf8;
typedef __attribute__((ext_vector_type(4))) float f4;
struct __align__(16) U8 { unsigned short s[8]; };

__device__ __forceinline__ unsigned short f2bf(float f) {
  union { float f; unsigned u; } v; v.f = f;
  unsigned r = v.u + 0x7fffu + ((v.u >> 16) & 1u);
  return (unsigned short)(r >> 16);
}

// ---------------------------------------------------------------------------
// Build per-(b,tile) images in ws, once.  Image = [K 16384 | Vt 16384] u16.
//   K : key*512 + ((c ^ (key&7))<<3), c = d>>3        (LDS-swizzled row-major)
//   Vt: 16384 + d*32 + ((g ^ ((d>>1)&3))<<3), g = key>>3  (transpose)
// ---------------------------------------------------------------------------
__global__ __launch_bounds__(256)
void build_images(const float* __restrict__ X, unsigned short* __restrict__ W) {
  __shared__ float sT[KV * Dd];  // 64 KB
  const int t = blockIdx.x, b = blockIdx.y, tid = threadIdx.x;
  const float* src = X + ((size_t)b * Nn + t * KV) * Dd;
#pragma unroll
  for (int i = 0; i < 16; ++i) {
    int idx = i * 256 + tid;
    *(float4*)(sT + idx * 4) = *(const float4*)(src + idx * 4);
  }
  __syncthreads();
  unsigned short* img = W + ((size_t)(b * NT + t) << 15);
#pragma unroll
  for (int i = 0; i < 8; ++i) {
    int idx = i * 256 + tid;
    int key = idx >> 6, c = idx & 63;
    const float* p = sT + key * Dd + c * 8;
    U8 v;
#pragma unroll
    for (int j = 0; j < 8; ++j) v.s[j] = f2bf(p[j]);
    *(U8*)(img + key * 512 + ((c ^ (key & 7)) << 3)) = v;
  }
#pragma unroll
  for (int i = 0; i < 8; ++i) {
    int idx = i * 256 + tid;
    int d = idx >> 2, g = idx & 3;
    U8 v;
#pragma unroll
    for (int e = 0; e < 8; ++e) v.s[e] = f2bf(sT[(g * 8 + e) * Dd + d]);
    *(U8*)(img + 16384 + d * 32 + ((g ^ ((d >> 1) & 3)) << 3)) = v;
  }
}

// ---------------------------------------------------------------------------
// D-split attention: 512 thr = 8 waves = (qg in {0,1}) x (dw in 0..3).
// Wave (qg,dw): 16 q-rows (q0 = qb*32 + qg*16), d-quarter [dw*128, dw*128+128).
//   acc o[8]x f4 = 32 regs, qf[4] = 16 regs -> fits the 128-VGPR cap of
//   512-thr blocks WITHOUT spill; 2 blocks/CU = 16 waves/CU.
// QK^T: per-wave partial over d-quarter -> LDS f4 exchange -> fixed-order sum
//   (bit-identical in all 4 dw waves -> shared sP multi-write is deterministic).
// PV: shared P x per-wave V d-quarter straight from L2 Vt image.
// ---------------------------------------------------------------------------
__global__ __launch_bounds__(512, 1)
void attn_ds(const unsigned short* __restrict__ W, const int* __restrict__ mask,
             float* __restrict__ out) {
  __shared__ unsigned short sK[16384];        // K image, 32 KB
  __shared__ f4 sS[2][4][2][64];              // partial-S exchange, 16 KB
  __shared__ unsigned short sP[2][16 * PPS];  // per-qg shared P, 2.6 KB

  const int tid  = threadIdx.x;
  const int wave = tid >> 6;
  const int qg = wave >> 2, dw = wave & 3;
  const int lane = tid & 63;
  const int lg = lane >> 4, ll = lane & 15;
  const int slot = lg * 16 + ll;              // 0..63
  const int bid = blockIdx.x;
  const int b = bid & 7;                      // XCD-batch affinity
  const int qb = bid >> 3;                    // 0..63
  const int q0 = qb * 32 + qg * 16;
  const int bN = b * NT;
  const float scale = 0.044194173824159216f;  // 1/sqrt(512)

  // Q fragments for this wave's d-quarter (from the K-images, same addr math)
  bf8 qf[4];
  {
    int qrow = q0 + ll;
    const unsigned short* qimg = W + ((size_t)(bN + (qrow >> 5)) << 15);
    int qk = qrow & 31;
#pragma unroll
    for (int ch = 0; ch < 4; ++ch) {
      int c = dw * 16 + ch * 4 + lg;
      qf[ch] = *(const bf8*)(qimg + qk * 512 + ((c ^ (qk & 7)) << 3));
    }
  }

  float bias[4];
#pragma unroll
  for (int r = 0; r < 4; ++r)
    bias[r] = (1.0f - (float)mask[b * Nn + q0 + lg * 4 + r]) * 1e9f;

  float m[4], lsum[4];
  f4 o[8];
#pragma unroll
  for (int r = 0; r < 4; ++r) { m[r] = -1e30f; lsum[r] = 0.0f; }
#pragma unroll
  for (int ct = 0; ct < 8; ++ct) o[ct] = (f4){0.f, 0.f, 0.f, 0.f};

  // prologue: stage K tile 0 (32 KB = 4 x 16B per thread)
  {
    const unsigned short* img0 = W + ((size_t)bN << 15);
#pragma unroll
    for (int i = 0; i < 4; ++i)
      *(U8*)(sK + (i * 512 + tid) * 8) = *(const U8*)(img0 + (i * 512 + tid) * 8);
  }
  __syncthreads();

  for (int t = 0; t < NT; ++t) {
    const bool pf = (t + 1 < NT);
    const unsigned short* gKn = W + ((size_t)(bN + t + 1) << 15);

    U8 stA[2];
    if (pf) {
      stA[0] = *(const U8*)(gKn + (0 * 512 + tid) * 8);
      stA[1] = *(const U8*)(gKn + (1 * 512 + tid) * 8);
    }

    // ---- QK^T partial over d-quarter: 8 MFMAs ----
    f4 s2[2];
    s2[0] = (f4){0.f, 0.f, 0.f, 0.f};
    s2[1] = (f4){0.f, 0.f, 0.f, 0.f};
#pragma unroll
    for (int ch = 0; ch < 4; ++ch) {
#pragma unroll
      for (int cc = 0; cc < 2; ++cc) {
        int key = cc * 16 + ll;
        int c = dw * 16 + ch * 4 + lg;
        bf8 kf = *(const bf8*)(sK + key * 512 + ((c ^ (key & 7)) << 3));
        s2[cc] = __builtin_amdgcn_mfma_f32_16x16x32_bf16(qf[ch], kf, s2[cc], 0, 0, 0);
      }
    }
    sS[qg][dw][0][slot] = s2[0];
    sS[qg][dw][1][slot] = s2[1];

    __syncthreads();  // bar A: all partial-S visible; all K reads done

    U8 stB[2];
    if (pf) {
      *(U8*)(sK + (0 * 512 + tid) * 8) = stA[0];
      *(U8*)(sK + (1 * 512 + tid) * 8) = stA[1];
      stB[0] = *(const U8*)(gKn + (2 * 512 + tid) * 8);
      stB[1] = *(const U8*)(gKn + (3 * 512 + tid) * 8);
    }

    // ---- fixed-order full-D sum (identical in all dw waves) ----
    f4 sum0 = ((sS[qg][0][0][slot] + sS[qg][1][0][slot]) + sS[qg][2][0][slot]) + sS[qg][3][0][slot];
    f4 sum1 = ((sS[qg][0][1][slot] + sS[qg][1][1][slot]) + sS[qg][2][1][slot]) + sS[qg][3][1][slot];

    float e2[2][4];
#pragma unroll
    for (int r = 0; r < 4; ++r) {
      e2[0][r] = sum0[r] * scale - bias[r];   // f32: masked rows -> exactly -1e9
      e2[1][r] = sum1[r] * scale - bias[r];
    }

    // ---- online softmax (replicated across dw; identical results) ----
    float tm[4];
#pragma unroll
    for (int r = 0; r < 4; ++r) tm[r] = fmaxf(e2[0][r], e2[1][r]);
#pragma unroll
    for (int off = 1; off < 16; off <<= 1)
#pragma unroll
      for (int r = 0; r < 4; ++r) tm[r] = fmaxf(tm[r], __shfl_xor(tm[r], off));

    float mn[4];
    bool change = false;
#pragma unroll
    for (int r = 0; r < 4; ++r) { mn[r] = fmaxf(m[r], tm[r]); change = change || (mn[r] > m[r]); }
    if (__any(change)) {
#pragma unroll
      for (int r = 0; r < 4; ++r) {
        float al = __expf(m[r] - mn[r]);
        lsum[r] *= al;
        m[r] = mn[r];
#pragma unroll
        for (int ct = 0; ct < 8; ++ct) o[ct][r] *= al;
      }
    }

    float ts[4] = {0.f, 0.f, 0.f, 0.f};
    unsigned short pb[2][4];
#pragma unroll
    for (int cc = 0; cc < 2; ++cc)
#pragma unroll
      for (int r = 0; r < 4; ++r) {
        float p = __expf(e2[cc][r] - m[r]);
        ts[r] += p;
        pb[cc][r] = f2bf(p);
      }
#pragma unroll
    for (int off = 1; off < 16; off <<= 1)
#pragma unroll
      for (int r = 0; r < 4; ++r) ts[r] += __shfl_xor(ts[r], off);
#pragma unroll
    for (int r = 0; r < 4; ++r) lsum[r] += ts[r];

    // ---- shared P (all 4 dw waves write bit-identical bytes) ----
    unsigned short* Pw = sP[qg];
#pragma unroll
    for (int cc = 0; cc < 2; ++cc)
#pragma unroll
      for (int r = 0; r < 4; ++r)
        Pw[(lg * 4 + r) * PPS + cc * 16 + ll] = pb[cc][r];
    bf8 af = *(const bf8*)(Pw + ll * PPS + lg * 8);

    // ---- PV: this wave's d-quarter of V straight from L2 ----
    const unsigned short* gV = W + ((size_t)(bN + t) << 15) + 16384;
    bf8 va[4];
#pragma unroll
    for (int g = 0; g < 2; ++g) {
#pragma unroll
      for (int j = 0; j < 4; ++j) {
        int ct = g * 4 + j;
        int d = dw * 128 + ct * 16 + ll;
        va[j] = *(const bf8*)(gV + d * 32 + ((lg ^ ((d >> 1) & 3)) << 3));
      }
#pragma unroll
      for (int j = 0; j < 4; ++j)
        o[g * 4 + j] = __builtin_amdgcn_mfma_f32_16x16x32_bf16(af, va[j], o[g * 4 + j], 0, 0, 0);
    }

    // write second half of next K tile (sK free since bar A)
    if (pf) {
      *(U8*)(sK + (2 * 512 + tid) * 8) = stB[0];
      *(U8*)(sK + (3 * 512 + tid) * 8) = stB[1];
    }
    __syncthreads();  // bar B: K writes, sS/sP reads all settled
  }

  // ---- epilogue: normalize, store this wave's 16q x 128d block ----
  float inv[4];
#pragma unroll
  for (int r = 0; r < 4; ++r) inv[r] = 1.0f / lsum[r];
#pragma unroll
  for (int ct = 0; ct < 8; ++ct)
#pragma unroll
    for (int r = 0; r < 4; ++r) {
      size_t row = (size_t)b * Nn + q0 + lg * 4 + r;
      out[row * Dd + dw * 128 + ct * 16 + ll] = o[ct][r] * inv[r];
    }
}

// ---------------------------------------------------------------------------
// Fallback (no usable ws): R10 structure, KV=64, in-kernel convert.
// ---------------------------------------------------------------------------
__global__ __launch_bounds__(256, 1)
void attn_fb(const float* __restrict__ Xf, const int* __restrict__ mask,
             float* __restrict__ out) {
  __shared__ unsigned short sKf[KVF * Dd];
  __shared__ unsigned short sVt[Dd * KVF];
  __shared__ unsigned short sPf[4][16 * PPF];

  const int tid  = threadIdx.x;
  const int wave = tid >> 6, lane = tid & 63;
  const int lg = lane >> 4, ll = lane & 15;
  const int b  = blockIdx.y;
  const int q0 = blockIdx.x * 64 + wave * 16;

  bf8 qf[16];
  {
    const size_t qoff = ((size_t)b * Nn + q0 + ll) * Dd;
#pragma unroll
    for (int ch = 0; ch < 16; ++ch) {
      int doff = ch * 32 + lg * 8;
      float4 a = *(const float4*)(Xf + qoff + doff);
      float4 c = *(const float4*)(Xf + qoff + doff + 4);
      bf8 tt;
      tt[0] = (short)f2bf(a.x); tt[1] = (short)f2bf(a.y);
      tt[2] = (short)f2bf(a.z); tt[3] = (short)f2bf(a.w);
      tt[4] = (short)f2bf(c.x); tt[5] = (short)f2bf(c.y);
      tt[6] = (short)f2bf(c.z); tt[7] = (short)f2bf(c.w);
      qf[ch] = tt;
    }
  }
  float bias[4];
#pragma unroll
  for (int r = 0; r < 4; ++r)
    bias[r] = (1.0f - (float)mask[b * Nn + q0 + lg * 4 + r]) * 1e9f;
  float m[4], lsum[4];
  f4 o[32];
#pragma unroll
  for (int r = 0; r < 4; ++r) { m[r] = -1e30f; lsum[r] = 0.0f; }
#pragma unroll
  for (int ct = 0; ct < 32; ++ct) o[ct] = (f4){0.f, 0.f, 0.f, 0.f};
  const float scale = 0.044194173824159216f;

  for (int t = 0; t < NTF; ++t) {
    __syncthreads();
    const size_t base = ((size_t)b * Nn + t * KVF) * Dd;
#pragma unroll
    for (int it = 0; it < 16; ++it) {
      int idx = it * 256 + tid;
      int key = idx >> 6, c = idx & 63;
      const float* sp = Xf + base + key * Dd + c * 8;
      float4 a = *(const float4*)(sp);
      float4 d2 = *(const float4*)(sp + 4);
      U8 v;
      v.s[0] = f2bf(a.x); v.s[1] = f2bf(a.y); v.s[2] = f2bf(a.z); v.s[3] = f2bf(a.w);
      v.s[4] = f2bf(d2.x); v.s[5] = f2bf(d2.y); v.s[6] = f2bf(d2.z); v.s[7] = f2bf(d2.w);
      *(U8*)(sKf + key * 512 + ((c ^ (key & 7)) << 3)) = v;
      int ko = key >> 3, k7 = key & 7;
#pragma unroll
      for (int j = 0; j < 8; ++j) {
        int dd = c * 8 + j;
        sVt[dd * 64 + ((ko ^ j ^ (c & 7)) << 3) + k7] = v.s[j];
      }
    }
    __syncthreads();

    f4 s[4];
#pragma unroll
    for (int cc = 0; cc < 4; ++cc) s[cc] = (f4){0.f, 0.f, 0.f, 0.f};
#pragma unroll
    for (int ch = 0; ch < 16; ++ch)
#pragma unroll
      for (int cc = 0; cc < 4; ++cc) {
        int key = cc * 16 + ll;
        bf8 kf = *(const bf8*)(sKf + key * 512 + (((ch * 4 + lg) ^ (key & 7)) << 3));
        s[cc] = __builtin_amdgcn_mfma_f32_16x16x32_bf16(qf[ch], kf, s[cc], 0, 0, 0);
      }

    float e[4][4];
#pragma unroll
    for (int cc = 0; cc < 4; ++cc)
#pragma unroll
      for (int r = 0; r < 4; ++r) e[cc][r] = s[cc][r] * scale - bias[r];
    float tm[4];
#pragma unroll
    for (int r = 0; r < 4; ++r)
      tm[r] = fmaxf(fmaxf(e[0][r], e[1][r]), fmaxf(e[2][r], e[3][r]));
#pragma unroll
    for (int off = 1; off < 16; off <<= 1)
#pragma unroll
      for (int r = 0; r < 4; ++r) tm[r] = fmaxf(tm[r], __shfl_xor(tm[r], off));
    float mn[4]; bool change = false;
#pragma unroll
    for (int r = 0; r < 4; ++r) { mn[r] = fmaxf(m[r], tm[r]); change = change || (mn[r] > m[r]); }
    if (__any(change)) {
#pragma unroll
      for (int r = 0; r < 4; ++r) {
        float al = __expf(m[r] - mn[r]);
        lsum[r] *= al; m[r] = mn[r];
#pragma unroll
        for (int ct = 0; ct < 32; ++ct) o[ct][r] *= al;
      }
    }
    float ts[4] = {0.f, 0.f, 0.f, 0.f};
    unsigned short pb[4][4];
#pragma unroll
    for (int cc = 0; cc < 4; ++cc)
#pragma unroll
      for (int r = 0; r < 4; ++r) {
        float p = __expf(e[cc][r] - m[r]);
        ts[r] += p; pb[cc][r] = f2bf(p);
      }
#pragma unroll
    for (int off = 1; off < 16; off <<= 1)
#pragma unroll
      for (int r = 0; r < 4; ++r) ts[r] += __shfl_xor(ts[r], off);
#pragma unroll
    for (int r = 0; r < 4; ++r) lsum[r] += ts[r];

    unsigned short* Pw = sPf[wave];
#pragma unroll
    for (int cc = 0; cc < 4; ++cc)
#pragma unroll
      for (int r = 0; r < 4; ++r)
        Pw[(lg * 4 + r) * PPF + cc * 16 + ll] = pb[cc][r];
#pragma unroll
    for (int kc = 0; kc < 2; ++kc) {
      bf8 af = *(const bf8*)(Pw + ll * PPF + kc * 32 + lg * 8);
#pragma unroll
      for (int ct = 0; ct < 32; ++ct) {
        int d = ct * 16 + ll;
        bf8 vf = *(const bf8*)(sVt + d * 64 + (((kc * 4 + lg) ^ (d & 7) ^ ((d >> 3) & 7)) << 3));
        o[ct] = __builtin_amdgcn_mfma_f32_16x16x32_bf16(af, vf, o[ct], 0, 0, 0);
      }
    }
  }
  float inv[4];
#pragma unroll
  for (int r = 0; r < 4; ++r) inv[r] = 1.0f / lsum[r];
#pragma unroll
  for (int ct = 0; ct < 32; ++ct)
#pragma unroll
    for (int r = 0; r < 4; ++r) {
      size_t row = (size_t)b * Nn + q0 + lg * 4 + r;
      out[row * Dd + ct * 16 + ll] = o[ct][r] * inv[r];
    }
}

extern "C" void kernel_launch(void* const* d_in, const int* in_sizes, int n_in,
                              void* d_out, int out_size, void* d_ws, size_t ws_size,
                              hipStream_t stream) {
  (void)in_sizes; (void)n_in; (void)out_size;
  const float* X  = (const float*)d_in[0];
  const int* mask = (const int*)d_in[1];
  float* out = (float*)d_out;

  const size_t szImg = (size_t)Bb * NT * 65536;  // 32 MiB of bf16 images
  if (ws_size >= szImg) {
    unsigned short* W = (unsigned short*)d_ws;
    build_images<<<dim3(NT, Bb), 256, 0, stream>>>(X, W);
    attn_ds<<<512, 512, 0, stream>>>(W, mask, out);
  } else {
    attn_fb<<<dim3(Nn / 64, Bb), 256, 0, stream>>>(X, mask, out);
  }
}